// Round 6
// baseline (4266.979 us; speedup 1.0000x reference)
//
#include <hip/hip_runtime.h>
#include <cstdint>

#define B_    8
#define T_    16384
#define NA_   512
#define A_    512
#define NIT_  32
#define NCH_  256          // 64-sample chunks per row
#define EPSV  1e-8f
#define WMAX  1664
#define XWPHYS 1880        // WMAX + 4*(WMAX/32) + pad
#define TP    16912        // padded length of each shifted packed-x copy

typedef unsigned long long u64;
typedef __attribute__((ext_vector_type(8))) short bf16x8;
typedef __attribute__((ext_vector_type(4))) float f32x4;

// ws float-offset layout (~13.8 MB total)
#define OFF_INV   0
#define OFF_SELA  512
#define OFF_SELT  768
#define OFF_SELV  1024
#define OFF_CM    1280        // u64[8*512*256] = 2,097,152 floats
#define OFF_RMA   2098432     // u64[4096]
#define OFF_RMB   2106624
#define OFF_XRA   2114816
#define OFF_XRB   2245888
#define OFF_DHH   2376960     // u32[512*512] (hi,hi) packed
#define OFF_DLL   2639104     // u32[512*512] (lo,lo) packed
#define OFF_XPS   2901248     // u32[4*8*TP]  (hi,lo) packed, 4 shifts
#define MAIN_NEED 3442432
// compact fallback layout
#define OFF_SXR   2048
#define OFF_SCAND (2048 + 131072)
#define S_NEED    (OFF_SCAND + 16)

__device__ __forceinline__ unsigned int encf(float f) {
    unsigned int u = __float_as_uint(f);
    return (u & 0x80000000u) ? ~u : (u | 0x80000000u);
}
__device__ __forceinline__ float decf(unsigned int e) {
    unsigned int u = (e & 0x80000000u) ? (e & 0x7fffffffu) : ~e;
    return __uint_as_float(u);
}
__device__ __forceinline__ u64 umax64(u64 a, u64 b) { return a > b ? a : b; }
__device__ __forceinline__ u64 enc64(float v, unsigned int flat) {
    return (((u64)encf(v)) << 32) | (unsigned int)~flat;
}
__device__ __forceinline__ u64 shfl_xor_u64(u64 v, int mask) {
    unsigned int lo = (unsigned int)v, hi = (unsigned int)(v >> 32);
    lo = __shfl_xor(lo, mask, 64);
    hi = __shfl_xor(hi, mask, 64);
    return (((u64)hi) << 32) | lo;
}
__device__ __forceinline__ u64 shfl_down_u64(u64 v, int off) {
    unsigned int lo = (unsigned int)v, hi = (unsigned int)(v >> 32);
    lo = __shfl_down(lo, off, 64);
    hi = __shfl_down(hi, off, 64);
    return (((u64)hi) << 32) | lo;
}
// bf16 round-to-nearest-even from fp32 (bit-level, no API deps)
__device__ __forceinline__ unsigned short f2bf(float v) {
    unsigned int u = __float_as_uint(v);
    return (unsigned short)((u + 0x7fffu + ((u >> 16) & 1u)) >> 16);
}

// ---------------- inv[a] = 1/(||d_a||+eps) ----------------
__global__ __launch_bounds__(64) void k_inv(const float* __restrict__ d, float* __restrict__ inv) {
    const int a = blockIdx.x, lane = threadIdx.x;
    const float* row = d + a * A_;
    float s = 0.f;
    for (int i = lane; i < A_; i += 64) { float v = row[i]; s = fmaf(v, v, s); }
    #pragma unroll
    for (int o = 32; o > 0; o >>= 1) s += __shfl_down(s, o, 64);
    if (lane == 0) inv[a] = 1.0f / (sqrtf(s) + EPSV);
}

// ---------------- d -> (hi,hi) and (lo,lo) packed-u32 arrays ----------------
__global__ __launch_bounds__(256) void k_split_d(const float* __restrict__ d,
                                                 unsigned int* __restrict__ dhh,
                                                 unsigned int* __restrict__ dll) {
    int id = blockIdx.x * 256 + threadIdx.x;           // 262144
    float v = d[id];
    unsigned short hb = f2bf(v);
    float hf = __uint_as_float((unsigned int)hb << 16);
    unsigned short lb = f2bf(v - hf);
    dhh[id] = (unsigned int)hb * 0x10001u;
    dll[id] = (unsigned int)lb * 0x10001u;
}

// ---------------- x -> 4 shifted copies of packed (hi|lo<<16), zero-padded ----------------
__global__ __launch_bounds__(256) void k_shift_x(const float* __restrict__ x,
                                                 unsigned int* __restrict__ xps) {
    int id = blockIdx.x * 256 + threadIdx.x;           // 4*B_*TP
    if (id >= 4 * B_ * TP) return;
    int i = id % TP, sb = id / TP;
    int b = sb % B_, s = sb / B_;
    int e = i + s;
    float v = (e < T_) ? x[b * T_ + e] : 0.f;
    unsigned short hb = f2bf(v);
    float hf = __uint_as_float((unsigned int)hb << 16);
    unsigned short lb = f2bf(v - hf);
    xps[id] = (unsigned int)hb | ((unsigned int)lb << 16);
}

// ---------------- full conv via MFMA (2-pass bf16 split) -> cm table ----------------
// wave tile: 16 atoms x 128 t; block: 64 atoms x 128 t; no LDS, no barriers.
__global__ __launch_bounds__(256) void k_conv(const unsigned int* __restrict__ dhh,
                                              const unsigned int* __restrict__ dll,
                                              const unsigned int* __restrict__ xps,
                                              const float* __restrict__ inv,
                                              u64* __restrict__ cm) {
    const int tid = threadIdx.x;
    const int w = tid >> 6, lane = tid & 63;
    const int c = lane & 15, q = lane >> 4;
    const int t0 = blockIdx.x * 128;
    const int a0 = blockIdx.y * 64 + w * 16;
    const int b  = blockIdx.z;

    // A-frag (d): lane row = a0+c, k' = 32*step + 8q+j  ->  j-chunk 4q..4q+3
    const unsigned int* dhp = dhh + (size_t)(a0 + c) * A_ + 4 * q;
    const unsigned int* dlp = dll + (size_t)(a0 + c) * A_ + 4 * q;
    // B-frag (x): col n = nt*16 + c; shift s = c&3 (constant/lane); aligned base
    const unsigned int* xpb = xps + (size_t)((c & 3) * B_ + b) * TP
                              + t0 + (c & ~3) + 4 * q;

    f32x4 acc[8];
    const f32x4 zero = {0.f, 0.f, 0.f, 0.f};
    #pragma unroll
    for (int nt = 0; nt < 8; ++nt) acc[nt] = zero;

    for (int j0 = 0; j0 < A_; j0 += 16) {              // 32 K'-steps of 32
        union { uint4 u; bf16x8 f; } ah, al;
        ah.u = *(const uint4*)(dhp + j0);
        al.u = *(const uint4*)(dlp + j0);
        #pragma unroll
        for (int nt = 0; nt < 8; ++nt) {
            union { uint4 u; bf16x8 f; } bx;
            bx.u = *(const uint4*)(xpb + j0 + nt * 16);
            // pass1: (hi(x)+lo(x))*hi(d); pass2: (hi(x)+lo(x))*lo(d)
            acc[nt] = __builtin_amdgcn_mfma_f32_16x16x32_bf16(ah.f, bx.f, acc[nt], 0, 0, 0);
            acc[nt] = __builtin_amdgcn_mfma_f32_16x16x32_bf16(al.f, bx.f, acc[nt], 0, 0, 0);
        }
    }

    // epilogue: C/D layout col=lane&15, row=4q+reg  -> chunk maxima
    float iv[4];
    #pragma unroll
    for (int r = 0; r < 4; ++r) iv[r] = inv[a0 + 4 * q + r];
    u64 m0[4] = {0, 0, 0, 0}, m1[4] = {0, 0, 0, 0};
    #pragma unroll
    for (int nt = 0; nt < 8; ++nt) {
        int t = t0 + nt * 16 + c;
        #pragma unroll
        for (int r = 0; r < 4; ++r) {
            float val = acc[nt][r] * iv[r];
            u64 e = enc64(val, (unsigned int)((a0 + 4 * q + r) * T_ + t));
            if (nt < 4) m0[r] = umax64(m0[r], e);
            else        m1[r] = umax64(m1[r], e);
        }
    }
    #pragma unroll
    for (int r = 0; r < 4; ++r) {
        #pragma unroll
        for (int mk = 1; mk < 16; mk <<= 1) {
            m0[r] = umax64(m0[r], shfl_xor_u64(m0[r], mk));
            m1[r] = umax64(m1[r], shfl_xor_u64(m1[r], mk));
        }
    }
    if (c == 0) {
        const int ch0 = t0 >> 6;
        #pragma unroll
        for (int r = 0; r < 4; ++r) {
            size_t row = (size_t)(b * NA_ + a0 + 4 * q + r) * NCH_;
            cm[row + ch0] = m0[r];
            cm[row + ch0 + 1] = m1[r];
        }
    }
}

// ---------------- rm from cm (4 rows per block, wave per row) ----------------
__global__ __launch_bounds__(256) void k_tables(const u64* __restrict__ cm, u64* __restrict__ rm) {
    const int row = blockIdx.x * 4 + (threadIdx.x >> 6);
    const int lane = threadIdx.x & 63;
    const u64* p = cm + (size_t)row * NCH_;
    u64 m = 0ull;
    #pragma unroll
    for (int k = 0; k < 4; ++k) m = umax64(m, p[lane + 64 * k]);
    #pragma unroll
    for (int o = 32; o > 0; o >>= 1) m = umax64(m, shfl_down_u64(m, o));
    if (lane == 0) rm[row] = m;
}

// ---------------- one full iteration: select + patch + window recompute + tables ----------------
__global__ __launch_bounds__(256) void k_iter(const float* __restrict__ xrPrev,
                                              float* __restrict__ xrNext,
                                              const float* __restrict__ d,
                                              const float* __restrict__ inv,
                                              u64* __restrict__ cm,
                                              const u64* __restrict__ rmPrev,
                                              u64* __restrict__ rmNext,
                                              int* __restrict__ selA,
                                              int* __restrict__ selT,
                                              float* __restrict__ selV,
                                              int it) {
    __shared__ u64 redU[256];
    __shared__ float xW[XWPHYS];
    __shared__ float dL[A_];
    const int aB = blockIdx.x, gb = blockIdx.y, tid = threadIdx.x;

    // phase A: argmax from rm (all blocks identical)
    const u64* rp = rmPrev + gb * NA_;
    redU[tid] = umax64(rp[tid], rp[tid + 256]);
    __syncthreads();
    for (int s = 128; s > 0; s >>= 1) {
        if (tid < s) redU[tid] = umax64(redU[tid], redU[tid + s]);
        __syncthreads();
    }
    const u64 win = redU[0];
    __syncthreads();
    const unsigned int enc = (unsigned int)(win >> 32);
    const unsigned int flat = ~(unsigned int)win;
    const int asel = (int)(flat >> 14);
    const int tsel = (int)(flat & (T_ - 1));
    const float v = decf(enc);
    if (aB == 0 && tid == 0) {
        selA[it * B_ + gb] = asel;
        selT[it * B_ + gb] = tsel;
        selV[it * B_ + gb] = v;
    }
    const int L = min(A_, (T_ - 1) - tsel);   // reference truncation quirk
    const float vv = v * inv[asel];

    // persist xr for next iter: block aB owns t in [aB*32, aB*32+32), patch fused
    if (tid < 32) {
        int t = aB * 32 + tid;
        float xv = xrPrev[gb * T_ + t];
        int o = t - tsel;
        if (o >= 0 && o < L) xv = fmaf(-vv, d[asel * A_ + o], xv);
        xrNext[gb * T_ + t] = xv;
    }

    if (L > 0) {
        const int tbeg = max(0, tsel - (A_ - 1));
        const int tend = tsel + L;              // exclusive, <= 16383
        const int ab = tbeg & ~63;              // chunk-aligned window
        const int ae = (tend + 63) & ~63;       // <= T_
        const int W = ae - ab;                  // <= 1152, multiple of 64
        const int nst = W + A_;                 // <= 1664

        // stage patched residual window; swizzle phys = i + 4*(i>>5):
        // thread slices stay 16B-aligned & consecutive -> ds_read_b128
        for (int i = tid; i < nst; i += 256) {
            int t = ab + i;
            float xv = (t < T_) ? xrPrev[gb * T_ + t] : 0.f;
            int o = t - tsel;
            if (o >= 0 && o < L) xv = fmaf(-vv, d[asel * A_ + o], xv);
            xW[i + ((i >> 5) << 2)] = xv;
        }
        for (int i = tid; i < A_; i += 256) dL[i] = d[aB * A_ + i];
        __syncthreads();

        const int base = tid * 8;               // 8 consecutive t per thread
        if (base < W) {
            const float iv = inv[aB];
            float acc[8] = {0.f, 0.f, 0.f, 0.f, 0.f, 0.f, 0.f, 0.f};
            float h[16];
            {
                const float4* p = (const float4*)&xW[base + ((base >> 5) << 2)];
                float4 a0v = p[0], a1v = p[1];
                h[0] = a0v.x; h[1] = a0v.y; h[2] = a0v.z; h[3] = a0v.w;
                h[4] = a1v.x; h[5] = a1v.y; h[6] = a1v.z; h[7] = a1v.w;
            }
            const float* pd = dL;
            for (int j = 0; j < A_; j += 8) {
                int ie = base + j + 8;
                const float4* p = (const float4*)&xW[ie + ((ie >> 5) << 2)];
                float4 c0 = p[0], c1 = p[1];
                h[8]  = c0.x; h[9]  = c0.y; h[10] = c0.z; h[11] = c0.w;
                h[12] = c1.x; h[13] = c1.y; h[14] = c1.z; h[15] = c1.w;
                const float4* pdv = (const float4*)pd;
                float4 d0 = pdv[0], d1 = pdv[1];
                float wv[8] = {d0.x, d0.y, d0.z, d0.w, d1.x, d1.y, d1.z, d1.w};
                #pragma unroll
                for (int u = 0; u < 8; ++u)
                    #pragma unroll
                    for (int k = 0; k < 8; ++k)
                        acc[k] = fmaf(h[u + k], wv[u], acc[k]);
                pd += 8;
                #pragma unroll
                for (int m = 0; m < 8; ++m) h[m] = h[m + 8];
            }
            // chunk max: 8 lanes (64 t) per chunk, then write cm
            u64 cc = 0ull;
            #pragma unroll
            for (int k = 0; k < 8; ++k) {
                unsigned int fl = (unsigned int)(aB * T_ + ab + base + k);
                cc = umax64(cc, enc64(acc[k] * iv, fl));
            }
            cc = umax64(cc, shfl_xor_u64(cc, 1));
            cc = umax64(cc, shfl_xor_u64(cc, 2));
            cc = umax64(cc, shfl_xor_u64(cc, 4));
            if ((tid & 7) == 0)
                cm[(size_t)(gb * NA_ + aB) * NCH_ + (ab >> 6) + (tid >> 3)] = cc;
        }
        __syncthreads();   // cm writes visible block-wide before rescan
    }

    // phase C: new row max from the 256 cm entries
    const u64* crow = cm + (size_t)(gb * NA_ + aB) * NCH_;
    redU[tid] = crow[tid];
    __syncthreads();
    for (int s = 128; s > 0; s >>= 1) {
        if (tid < s) redU[tid] = umax64(redU[tid], redU[tid + s]);
        __syncthreads();
    }
    if (tid == 0) rmNext[gb * NA_ + aB] = redU[0];
}

// ---------------- slow fallback (tiny ws): residual-space recompute ----------------
__global__ void s_init(const float* __restrict__ x, float* __restrict__ xr,
                       u64* __restrict__ cand) {
    int i = blockIdx.x * 256 + threadIdx.x;
    if (i < B_ * T_) xr[i] = x[i];
    if (i < B_) cand[i] = 0ull;
}
__global__ __launch_bounds__(256) void s_scan(const float* __restrict__ xr,
                                              const float* __restrict__ d,
                                              const float* __restrict__ inv,
                                              u64* __restrict__ cand) {
    __shared__ float dLs[A_];
    __shared__ u64 redU[256];
    const int aB = blockIdx.x, b = blockIdx.y, tid = threadIdx.x;
    const float iv = inv[aB];
    for (int i = tid; i < A_; i += 256) dLs[i] = d[aB * A_ + i] * iv;
    __syncthreads();
    const float* xb = xr + b * T_;
    u64 best = 0ull;
    for (int t = tid; t < T_; t += 256) {
        float acc = 0.f;
        int lim = min(A_, T_ - t);
        for (int i = 0; i < lim; ++i) acc = fmaf(dLs[i], xb[t + i], acc);
        best = umax64(best, enc64(acc, (unsigned int)(aB * T_ + t)));
    }
    redU[tid] = best;
    __syncthreads();
    for (int s = 128; s > 0; s >>= 1) {
        if (tid < s) redU[tid] = umax64(redU[tid], redU[tid + s]);
        __syncthreads();
    }
    if (tid == 0) atomicMax(&cand[b], redU[0]);
}
__global__ void s_apply(float* __restrict__ xr, const float* __restrict__ d,
                        const float* __restrict__ inv, u64* __restrict__ cand,
                        int* selA, int* selT, float* selV, int it) {
    const int b = blockIdx.x, tid = threadIdx.x;
    u64 win = cand[b];
    unsigned int enc = (unsigned int)(win >> 32);
    unsigned int flat = ~(unsigned int)win;
    int a = (int)(flat >> 14), t = (int)(flat & (T_ - 1));
    float v = decf(enc);
    if (tid == 0) { selA[it * B_ + b] = a; selT[it * B_ + b] = t; selV[it * B_ + b] = v; }
    float vvl = v * inv[a];
    int L = min(A_, (T_ - 1) - t);
    for (int o = tid; o < L; o += 256) xr[b * T_ + t + o] -= vvl * d[a * A_ + o];
    if (tid == 0) cand[b] = 0ull;
}

// ---------------- reconstruct (residual, recon) from selections ----------------
__global__ __launch_bounds__(256) void k_final(const float* __restrict__ x,
                                               const float* __restrict__ d,
                                               const int* __restrict__ selA,
                                               const int* __restrict__ selT,
                                               const float* __restrict__ selV,
                                               const float* __restrict__ inv,
                                               float* __restrict__ out) {
    const int gid = blockIdx.x * 256 + threadIdx.x;
    const int b = gid >> 14;
    const int t = gid & (T_ - 1);
    float r = x[gid];
    float rec = 0.f;
    for (int k = 0; k < NIT_; ++k) {           // sequential: reference fp order
        int a  = selA[k * B_ + b];
        int ts = selT[k * B_ + b];
        float vvl = selV[k * B_ + b] * inv[a];
        int o = t - ts;
        int L = min(A_, (T_ - 1) - ts);
        if (o >= 0 && o < L) {
            float c = vvl * d[a * A_ + o];
            r -= c;
            rec += c;
        }
    }
    out[gid] = r;
    out[B_ * T_ + gid] = rec;
}

extern "C" void kernel_launch(void* const* d_in, const int* in_sizes, int n_in,
                              void* d_out, int out_size, void* d_ws, size_t ws_size,
                              hipStream_t stream) {
    const float* x = (const float*)d_in[0];
    const float* d = (const float*)d_in[1];
    float* out = (float*)d_out;
    float* ws = (float*)d_ws;
    const size_t wsf = ws_size / sizeof(float);

    float* inv  = ws + OFF_INV;
    int*   selA = (int*)(ws + OFF_SELA);
    int*   selT = (int*)(ws + OFF_SELT);
    float* selV = ws + OFF_SELV;

    if (wsf < (size_t)S_NEED) return;   // hopeless

    k_inv<<<dim3(NA_), dim3(64), 0, stream>>>(d, inv);

    if (wsf >= (size_t)MAIN_NEED) {
        u64* cm  = (u64*)(ws + OFF_CM);
        u64* rmA = (u64*)(ws + OFF_RMA);
        u64* rmB = (u64*)(ws + OFF_RMB);
        float* xrA = ws + OFF_XRA;
        float* xrB = ws + OFF_XRB;
        unsigned int* dhh = (unsigned int*)(ws + OFF_DHH);
        unsigned int* dll = (unsigned int*)(ws + OFF_DLL);
        unsigned int* xps = (unsigned int*)(ws + OFF_XPS);

        k_split_d<<<dim3(NA_ * A_ / 256), dim3(256), 0, stream>>>(d, dhh, dll);
        k_shift_x<<<dim3((4 * B_ * TP + 255) / 256), dim3(256), 0, stream>>>(x, xps);
        hipMemcpyAsync(xrA, x, (size_t)B_ * T_ * sizeof(float),
                       hipMemcpyDeviceToDevice, stream);
        k_conv<<<dim3(T_ / 128, NA_ / 64, B_), dim3(256), 0, stream>>>(dhh, dll, xps, inv, cm);
        k_tables<<<dim3(B_ * NA_ / 4), dim3(256), 0, stream>>>(cm, rmA);
        for (int it = 0; it < NIT_; ++it) {
            const float* xp = (it & 1) ? xrB : xrA;
            float*       xn = (it & 1) ? xrA : xrB;
            const u64*   ro = (it & 1) ? rmB : rmA;
            u64*         rn = (it & 1) ? rmA : rmB;
            k_iter<<<dim3(NA_, B_), dim3(256), 0, stream>>>(xp, xn, d, inv, cm, ro, rn,
                                                            selA, selT, selV, it);
        }
    } else {
        float* xr = ws + OFF_SXR;
        u64* cand = (u64*)(ws + OFF_SCAND);
        s_init<<<dim3((B_ * T_ + 255) / 256), dim3(256), 0, stream>>>(x, xr, cand);
        for (int it = 0; it < NIT_; ++it) {
            s_scan<<<dim3(NA_, B_), dim3(256), 0, stream>>>(xr, d, inv, cand);
            s_apply<<<dim3(B_), dim3(256), 0, stream>>>(xr, d, inv, cand, selA, selT, selV, it);
        }
    }

    k_final<<<dim3(B_ * T_ / 256), dim3(256), 0, stream>>>(x, d, selA, selT, selV, inv, out);
}

// Round 7
// 2320.673 us; speedup vs baseline: 1.8387x; 1.8387x over previous
//
#include <hip/hip_runtime.h>
#include <cstdint>

#define B_    8
#define T_    16384
#define NA_   512
#define A_    512
#define NIT_  32
#define NCH_  256           // 64-sample chunks per row
#define EPSV  1e-8f
#define TPAD  16928         // padded per-batch length of xhh/xll (u32 each)

typedef unsigned long long u64;
typedef __attribute__((ext_vector_type(8))) short bf16x8;
typedef __attribute__((ext_vector_type(4))) float f32x4;

// ws float-offset layout (11.1 MB total)
#define OFF_INV   0
#define OFF_SELA  512
#define OFF_SELT  768
#define OFF_SELV  1024
#define OFF_CM    1280        // u64[8*512*256] -> 2,097,152 floats
#define OFF_RM    2098432     // u64[4096]
#define OFF_XR    2106624     // f32[8*16384]
#define OFF_DPK   2237696     // u32[512*512]  d as (hi|lo<<16)
#define OFF_XHH   2499840     // u32[8*TPAD]   x as (hi|hi)
#define OFF_XLL   2635264     // u32[8*TPAD]   x as (lo|lo)
#define MAIN_NEED 2770688
// compact fallback layout
#define OFF_SXR   OFF_CM
#define OFF_SCAND (OFF_CM + 131072)
#define S_NEED    (OFF_SCAND + 16)

__device__ __forceinline__ unsigned int encf(float f) {
    unsigned int u = __float_as_uint(f);
    return (u & 0x80000000u) ? ~u : (u | 0x80000000u);
}
__device__ __forceinline__ float decf(unsigned int e) {
    unsigned int u = (e & 0x80000000u) ? (e & 0x7fffffffu) : ~e;
    return __uint_as_float(u);
}
__device__ __forceinline__ u64 umax64(u64 a, u64 b) { return a > b ? a : b; }
__device__ __forceinline__ u64 enc64(float v, unsigned int flat) {
    return (((u64)encf(v)) << 32) | (unsigned int)~flat;
}
__device__ __forceinline__ u64 shfl_xor_u64(u64 v, int mask) {
    unsigned int lo = (unsigned int)v, hi = (unsigned int)(v >> 32);
    lo = __shfl_xor(lo, mask, 64);
    hi = __shfl_xor(hi, mask, 64);
    return (((u64)hi) << 32) | lo;
}
__device__ __forceinline__ u64 shfl_down_u64(u64 v, int off) {
    unsigned int lo = (unsigned int)v, hi = (unsigned int)(v >> 32);
    lo = __shfl_down(lo, off, 64);
    hi = __shfl_down(hi, off, 64);
    return (((u64)hi) << 32) | lo;
}
// bf16 round-to-nearest-even from fp32
__device__ __forceinline__ unsigned short f2bf(float v) {
    unsigned int u = __float_as_uint(v);
    return (unsigned short)((u + 0x7fffu + ((u >> 16) & 1u)) >> 16);
}

// ---------------- inv[a] = 1/(||d_a||+eps) ----------------
__global__ __launch_bounds__(64) void k_inv(const float* __restrict__ d, float* __restrict__ inv) {
    const int a = blockIdx.x, lane = threadIdx.x;
    const float* row = d + a * A_;
    float s = 0.f;
    for (int i = lane; i < A_; i += 64) { float v = row[i]; s = fmaf(v, v, s); }
    #pragma unroll
    for (int o = 32; o > 0; o >>= 1) s += __shfl_down(s, o, 64);
    if (lane == 0) inv[a] = 1.0f / (sqrtf(s) + EPSV);
}

// ---------------- d -> packed (hi | lo<<16) ----------------
__global__ __launch_bounds__(256) void k_split_d(const float* __restrict__ d,
                                                 unsigned int* __restrict__ dpk) {
    int id = blockIdx.x * 256 + threadIdx.x;           // 262144
    float v = d[id];
    unsigned short hb = f2bf(v);
    unsigned short lb = f2bf(v - __uint_as_float((unsigned int)hb << 16));
    dpk[id] = (unsigned int)hb | ((unsigned int)lb << 16);
}

// ---------------- x -> duplicated-pair arrays (hi,hi) / (lo,lo), zero-padded ----------------
__global__ __launch_bounds__(256) void k_split_x(const float* __restrict__ x,
                                                 unsigned int* __restrict__ xhh,
                                                 unsigned int* __restrict__ xll) {
    int id = blockIdx.x * 256 + threadIdx.x;           // 8*TPAD = 135424
    int b = id / TPAD, i = id - b * TPAD;
    float v = (i < T_) ? x[b * T_ + i] : 0.f;
    unsigned short hb = f2bf(v);
    unsigned short lb = f2bf(v - __uint_as_float((unsigned int)hb << 16));
    xhh[id] = (unsigned int)hb * 0x10001u;
    xll[id] = (unsigned int)lb * 0x10001u;
}

// ---------------- core: one wave computes 64 atoms x 64 t, writes cm chunk maxima ----------------
__device__ __forceinline__ void conv_tile(int a_base, int t0, int gb,
                                          const unsigned int* __restrict__ dpk,
                                          const unsigned int* __restrict__ xhh,
                                          const unsigned int* __restrict__ xll,
                                          const float* __restrict__ inv,
                                          u64* __restrict__ cm) {
    const int lane = threadIdx.x & 63;
    const int c = lane & 15, q = lane >> 4;

    const unsigned int* Ap[4];
    #pragma unroll
    for (int at = 0; at < 4; ++at)
        Ap[at] = dpk + ((a_base + 16 * at + c) << 9) + 4 * q;
    const unsigned int* Bh = xhh + gb * TPAD + t0 + c + 4 * q;
    const unsigned int* Bl = xll + gb * TPAD + t0 + c + 4 * q;

    f32x4 acc[4][4];
    const f32x4 zero = {0.f, 0.f, 0.f, 0.f};
    #pragma unroll
    for (int at = 0; at < 4; ++at)
        #pragma unroll
        for (int tt = 0; tt < 4; ++tt) acc[at][tt] = zero;

    for (int j0 = 0; j0 < A_; j0 += 16) {              // 16 real samples / step
        union { uint4 u; bf16x8 f; } Af[4];
        #pragma unroll
        for (int at = 0; at < 4; ++at) Af[at].u = *(const uint4*)(Ap[at] + j0);
        #pragma unroll
        for (int tt = 0; tt < 4; ++tt) {
            union { uint4 u; bf16x8 f; } bh, bl;
            const unsigned int* ph = Bh + 16 * tt + j0;
            const unsigned int* pl = Bl + 16 * tt + j0;
            bh.u.x = ph[0]; bh.u.y = ph[1]; bh.u.z = ph[2]; bh.u.w = ph[3];
            bl.u.x = pl[0]; bl.u.y = pl[1]; bl.u.z = pl[2]; bl.u.w = pl[3];
            #pragma unroll
            for (int at = 0; at < 4; ++at) {
                acc[at][tt] = __builtin_amdgcn_mfma_f32_16x16x32_bf16(Af[at].f, bh.f, acc[at][tt], 0, 0, 0);
                acc[at][tt] = __builtin_amdgcn_mfma_f32_16x16x32_bf16(Af[at].f, bl.f, acc[at][tt], 0, 0, 0);
            }
        }
    }

    // epilogue: D row = 4q+r (atom within tile), col = c (t within tile)
    const int ch = t0 >> 6;
    #pragma unroll
    for (int at = 0; at < 4; ++at) {
        #pragma unroll
        for (int r = 0; r < 4; ++r) {
            const int atom = a_base + 16 * at + 4 * q + r;
            const float iv = inv[atom];
            u64 m = 0ull;
            #pragma unroll
            for (int tt = 0; tt < 4; ++tt) {
                int t = t0 + 16 * tt + c;
                m = umax64(m, enc64(acc[at][tt][r] * iv, (unsigned int)(atom * T_ + t)));
            }
            m = umax64(m, shfl_xor_u64(m, 1));
            m = umax64(m, shfl_xor_u64(m, 2));
            m = umax64(m, shfl_xor_u64(m, 4));
            m = umax64(m, shfl_xor_u64(m, 8));
            if (c == 0)
                cm[((size_t)(gb * NA_ + atom) << 8) + ch] = m;
        }
    }
}

// ---------------- full conv: grid (64 t-groups, 8 atom-groups, 8 b); wave = one t-chunk ----------------
__global__ __launch_bounds__(256) void k_conv(const unsigned int* __restrict__ dpk,
                                              const unsigned int* __restrict__ xhh,
                                              const unsigned int* __restrict__ xll,
                                              const float* __restrict__ inv,
                                              u64* __restrict__ cm) {
    const int t0 = ((blockIdx.x << 2) + (threadIdx.x >> 6)) << 6;
    conv_tile(blockIdx.y * 64, t0, blockIdx.z, dpk, xhh, xll, inv, cm);
}

// ---------------- windowed conv for one iteration ----------------
__global__ __launch_bounds__(256) void k_wconv(const unsigned int* __restrict__ dpk,
                                               const unsigned int* __restrict__ xhh,
                                               const unsigned int* __restrict__ xll,
                                               const float* __restrict__ inv,
                                               u64* __restrict__ cm,
                                               const int* __restrict__ selT,
                                               int it) {
    const int gb = blockIdx.z;
    const int tsel = selT[it * B_ + gb];
    const int L = min(A_, (T_ - 1) - tsel);
    if (L <= 0) return;                                 // residual unchanged
    const int tbeg = max(0, tsel - (A_ - 1));
    const int ab = tbeg & ~63;
    const int ae = (tsel + L + 63) & ~63;               // <= T_
    const int t0 = ab + (((blockIdx.x << 2) + (threadIdx.x >> 6)) << 6);
    if (t0 >= ae) return;
    conv_tile(blockIdx.y * 64, t0, gb, dpk, xhh, xll, inv, cm);
}

// ---------------- rm from cm (4 rows per block, wave per row) ----------------
__global__ __launch_bounds__(256) void k_tables(const u64* __restrict__ cm, u64* __restrict__ rm) {
    const int row = blockIdx.x * 4 + (threadIdx.x >> 6);
    const int lane = threadIdx.x & 63;
    const u64* p = cm + ((size_t)row << 8);
    u64 m = 0ull;
    #pragma unroll
    for (int k = 0; k < 4; ++k) m = umax64(m, p[lane + 64 * k]);
    #pragma unroll
    for (int o = 32; o > 0; o >>= 1) m = umax64(m, shfl_down_u64(m, o));
    if (lane == 0) rm[row] = m;
}

// ---------------- per-iteration: selection + in-place patch + bf16 re-split ----------------
__global__ __launch_bounds__(256) void k_patch(const u64* __restrict__ rm,
                                               const float* __restrict__ d,
                                               const float* __restrict__ inv,
                                               float* __restrict__ xr,
                                               unsigned int* __restrict__ xhh,
                                               unsigned int* __restrict__ xll,
                                               int* __restrict__ selA,
                                               int* __restrict__ selT,
                                               float* __restrict__ selV,
                                               int it) {
    __shared__ u64 redU[256];
    const int b = blockIdx.x, tid = threadIdx.x;
    const u64* rp = rm + b * NA_;
    redU[tid] = umax64(rp[tid], rp[tid + 256]);
    __syncthreads();
    for (int s = 128; s > 0; s >>= 1) {
        if (tid < s) redU[tid] = umax64(redU[tid], redU[tid + s]);
        __syncthreads();
    }
    const u64 win = redU[0];
    const unsigned int enc = (unsigned int)(win >> 32);
    const unsigned int flat = ~(unsigned int)win;
    const int asel = (int)(flat >> 14);
    const int tsel = (int)(flat & (T_ - 1));
    const float v = decf(enc);
    if (tid == 0) {
        selA[it * B_ + b] = asel;
        selT[it * B_ + b] = tsel;
        selV[it * B_ + b] = v;
    }
    const int L = min(A_, (T_ - 1) - tsel);  // reference truncation quirk
    if (L <= 0) return;
    const float vv = v * inv[asel];
    for (int i = tid; i < L; i += 256) {
        int idx = tsel + i;
        float nv = xr[b * T_ + idx] - vv * d[asel * A_ + i];
        xr[b * T_ + idx] = nv;
        unsigned short hb = f2bf(nv);
        unsigned short lb = f2bf(nv - __uint_as_float((unsigned int)hb << 16));
        xhh[b * TPAD + idx] = (unsigned int)hb * 0x10001u;
        xll[b * TPAD + idx] = (unsigned int)lb * 0x10001u;
    }
}

// ---------------- slow fallback (tiny ws): residual-space recompute ----------------
__global__ void s_init(const float* __restrict__ x, float* __restrict__ xr,
                       u64* __restrict__ cand) {
    int i = blockIdx.x * 256 + threadIdx.x;
    if (i < B_ * T_) xr[i] = x[i];
    if (i < B_) cand[i] = 0ull;
}
__global__ __launch_bounds__(256) void s_scan(const float* __restrict__ xr,
                                              const float* __restrict__ d,
                                              const float* __restrict__ inv,
                                              u64* __restrict__ cand) {
    __shared__ float dLs[A_];
    __shared__ u64 redU[256];
    const int aB = blockIdx.x, b = blockIdx.y, tid = threadIdx.x;
    const float iv = inv[aB];
    for (int i = tid; i < A_; i += 256) dLs[i] = d[aB * A_ + i] * iv;
    __syncthreads();
    const float* xb = xr + b * T_;
    u64 best = 0ull;
    for (int t = tid; t < T_; t += 256) {
        float acc = 0.f;
        int lim = min(A_, T_ - t);
        for (int i = 0; i < lim; ++i) acc = fmaf(dLs[i], xb[t + i], acc);
        best = umax64(best, enc64(acc, (unsigned int)(aB * T_ + t)));
    }
    redU[tid] = best;
    __syncthreads();
    for (int s = 128; s > 0; s >>= 1) {
        if (tid < s) redU[tid] = umax64(redU[tid], redU[tid + s]);
        __syncthreads();
    }
    if (tid == 0) atomicMax(&cand[b], redU[0]);
}
__global__ void s_apply(float* __restrict__ xr, const float* __restrict__ d,
                        const float* __restrict__ inv, u64* __restrict__ cand,
                        int* selA, int* selT, float* selV, int it) {
    const int b = blockIdx.x, tid = threadIdx.x;
    u64 win = cand[b];
    unsigned int enc = (unsigned int)(win >> 32);
    unsigned int flat = ~(unsigned int)win;
    int a = (int)(flat >> 14), t = (int)(flat & (T_ - 1));
    float v = decf(enc);
    if (tid == 0) { selA[it * B_ + b] = a; selT[it * B_ + b] = t; selV[it * B_ + b] = v; }
    float vvl = v * inv[a];
    int L = min(A_, (T_ - 1) - t);
    for (int o = tid; o < L; o += 256) xr[b * T_ + t + o] -= vvl * d[a * A_ + o];
    if (tid == 0) cand[b] = 0ull;
}

// ---------------- reconstruct (residual, recon) from selections ----------------
__global__ __launch_bounds__(256) void k_final(const float* __restrict__ x,
                                               const float* __restrict__ d,
                                               const int* __restrict__ selA,
                                               const int* __restrict__ selT,
                                               const float* __restrict__ selV,
                                               const float* __restrict__ inv,
                                               float* __restrict__ out) {
    const int gid = blockIdx.x * 256 + threadIdx.x;
    const int b = gid >> 14;
    const int t = gid & (T_ - 1);
    float r = x[gid];
    float rec = 0.f;
    for (int k = 0; k < NIT_; ++k) {           // sequential: reference fp order
        int a  = selA[k * B_ + b];
        int ts = selT[k * B_ + b];
        float vvl = selV[k * B_ + b] * inv[a];
        int o = t - ts;
        int L = min(A_, (T_ - 1) - ts);
        if (o >= 0 && o < L) {
            float c = vvl * d[a * A_ + o];
            r -= c;
            rec += c;
        }
    }
    out[gid] = r;
    out[B_ * T_ + gid] = rec;
}

extern "C" void kernel_launch(void* const* d_in, const int* in_sizes, int n_in,
                              void* d_out, int out_size, void* d_ws, size_t ws_size,
                              hipStream_t stream) {
    const float* x = (const float*)d_in[0];
    const float* d = (const float*)d_in[1];
    float* out = (float*)d_out;
    float* ws = (float*)d_ws;
    const size_t wsf = ws_size / sizeof(float);

    float* inv  = ws + OFF_INV;
    int*   selA = (int*)(ws + OFF_SELA);
    int*   selT = (int*)(ws + OFF_SELT);
    float* selV = ws + OFF_SELV;

    if (wsf < (size_t)S_NEED) return;   // hopeless

    k_inv<<<dim3(NA_), dim3(64), 0, stream>>>(d, inv);

    if (wsf >= (size_t)MAIN_NEED) {
        u64* cm = (u64*)(ws + OFF_CM);
        u64* rm = (u64*)(ws + OFF_RM);
        float* xr = ws + OFF_XR;
        unsigned int* dpk = (unsigned int*)(ws + OFF_DPK);
        unsigned int* xhh = (unsigned int*)(ws + OFF_XHH);
        unsigned int* xll = (unsigned int*)(ws + OFF_XLL);

        k_split_d<<<dim3(NA_ * A_ / 256), dim3(256), 0, stream>>>(d, dpk);
        k_split_x<<<dim3(B_ * TPAD / 256), dim3(256), 0, stream>>>(x, xhh, xll);
        hipMemcpyAsync(xr, x, (size_t)B_ * T_ * sizeof(float),
                       hipMemcpyDeviceToDevice, stream);
        k_conv<<<dim3(64, 8, B_), dim3(256), 0, stream>>>(dpk, xhh, xll, inv, cm);
        k_tables<<<dim3(B_ * NA_ / 4), dim3(256), 0, stream>>>(cm, rm);
        for (int it = 0; it < NIT_; ++it) {
            k_patch<<<dim3(B_), dim3(256), 0, stream>>>(rm, d, inv, xr, xhh, xll,
                                                        selA, selT, selV, it);
            k_wconv<<<dim3(5, 8, B_), dim3(256), 0, stream>>>(dpk, xhh, xll, inv, cm, selT, it);
            k_tables<<<dim3(B_ * NA_ / 4), dim3(256), 0, stream>>>(cm, rm);
        }
    } else {
        float* xr = ws + OFF_SXR;
        u64* cand = (u64*)(ws + OFF_SCAND);
        s_init<<<dim3((B_ * T_ + 255) / 256), dim3(256), 0, stream>>>(x, xr, cand);
        for (int it = 0; it < NIT_; ++it) {
            s_scan<<<dim3(NA_, B_), dim3(256), 0, stream>>>(xr, d, inv, cand);
            s_apply<<<dim3(B_), dim3(256), 0, stream>>>(xr, d, inv, cand, selA, selT, selV, it);
        }
    }

    k_final<<<dim3(B_ * T_ / 256), dim3(256), 0, stream>>>(x, d, selA, selT, selV, inv, out);
}